// Round 4
// baseline (228.344 us; speedup 1.0000x reference)
//
#include <hip/hip_runtime.h>

// YOLO 1D (audio) detection decoder, CENTER_DURATION encoding.
// Input  x: [B=32, G=131072, F=8] fp32 (8 floats / cell, 32B-aligned)
// Output   : fragments [B, G, 7] fp32, then mask [B, G] fp32 (1.0/0.0),
//            concatenated flat in d_out (tuple return order).
//
// History (measured):
//  r0: per-cell f4-pair loads (lane-stride 32B) + LDS frag + scalar stores:
//      kernel ~79-81 us.
//  r1: CPT=4 lane-private 128B records: 87 us (64-line VMEM requests).
//  r3: r0 loads + dense nt f4 stores via LDS: ~79 us. => stores exonerated;
//      the r0/r3 invariant is the HALF-LINE load pattern (each dwordx4
//      touches 32 lines, 16B used per line; 2.6 TB/s vs 6.8 TB/s fills).
//
// This version: FULLY DENSE loads. Thread t loads f4 #t and #t+256 of the
// block's input region (lane-stride 16B: every 64B line consumed by 4 lanes
// in ONE instruction; two instruction-strided loads double per-thread MLP).
// A thread therefore owns HALF a cell: even lanes {conf,x1,x2,x3} (compute
// start/end + mask), odd lanes {x4..x7} (pass-through). The single
// cross-lane dependency (conf for odd lanes) is one __shfl_xor. Outputs are
// staged in LDS with 4 predicated writes per f4 (parity-selected addr/val,
// no divergent branch):
//   w0..w2: dword 7c+{0,1,2}+3p  -> residues 7j / 7j+3 etc: 2-way = free
//   w3:     p ? frag 7c+6 : mask[c] -> all-32-banks x2     : 2-way = free
// Write-back: identical dense sweep as r3 — 512 f4/block (448 frag + 64
// mask, wave-aligned split), nontemporal so the output stream doesn't evict
// the L3-resident input (L3 serves ~half the input re-read: FETCH ~65 GB).
//
// __fadd_rn/__fmul_rn block FMA contraction so rintf (round-nearest-even,
// = jnp.round) sees bit-identical pre-round values vs the JAX reference.
// halfd = x2 * 524288.0f is exact (pure power-of-two scaling). Odd lanes
// compute garbage start/end from x5/x6 but discard via select (no traps).

constexpr int BLOCK = 256;
constexpr int F_OUT = 7;
constexpr int CPB   = 256;               // cells per block (= BLOCK*2 f4 / 2)

typedef float f32x4 __attribute__((ext_vector_type(4)));

__global__ __launch_bounds__(BLOCK) void yolo_decode_kernel(
    const f32x4* __restrict__ in4,       // [total_cells * 2] float4
    f32x4* __restrict__ frag4,           // frag region as float4
    f32x4* __restrict__ mask4,           // mask region as float4
    int g_mask,                          // G - 1 (G is a power of two)
    float cell_coef,                     // INPUT_LENGTH / G   (= 8.0f)
    float half_coef)                     // INPUT_LENGTH * 0.5 (= 524288.0f)
{
    // 1792 frag dwords + 256 mask dwords = 2048 dwords = 8 KB.
    __shared__ float s[CPB * F_OUT + CPB];

    const int tid       = threadIdx.x;
    const int p         = tid & 1;               // 0: fields 0-3, 1: fields 4-7
    const int cell_base = blockIdx.x * CPB;

    // Dense loads: 512 f4 per block, lane-stride 16 B, two 4KB-apart
    // instructions per thread (independent -> both in flight).
    const size_t f4base = (size_t)blockIdx.x * (2 * CPB);
    const f32x4 v0 = in4[f4base + tid];          // half of cell c0
    const f32x4 v1 = in4[f4base + BLOCK + tid];  // half of cell c0 + 128

    const int c0 = tid >> 1;                     // local cell of v0
    #pragma unroll
    for (int h = 0; h < 2; ++h) {
        const f32x4 v  = h ? v1 : v0;
        const int   cl = h ? (c0 + BLOCK / 2) : c0;      // local cell index
        const int   c  = cell_base + cl;                 // global cell

        const float confo = __shfl_xor(v.x, 1);          // partner's .x
        const bool  m     = (p ? confo : v.x) >= 0.5f;

        // Even-lane decode (odd lanes: discarded garbage).
        const float g      = (float)(c & g_mask);
        const float center = __fmul_rn(__fadd_rn(g, v.y), cell_coef);
        const float halfd  = __fmul_rn(v.z, half_coef);  // exact pow2 scale
        const float s_val  = rintf(__fadd_rn(center, -halfd));  // v_rndne_f32
        const float e_val  = rintf(__fadd_rn(center,  halfd));

        // 4 predicated LDS writes, parity-selected (no divergence).
        const int base = cl * F_OUT + p * 3;
        s[base + 0] = m ? (p ? v.x : s_val) : 0.0f;
        s[base + 1] = m ? (p ? v.y : e_val) : 0.0f;
        s[base + 2] = m ? (p ? v.z : v.w ) : 0.0f;
        const int   a3 = p ? (cl * F_OUT + 6) : (CPB * F_OUT + cl);
        const float w3 = p ? (m ? v.w : 0.0f) : (m ? 1.0f : 0.0f);
        s[a3] = w3;
    }

    __syncthreads();

    // 512 float4 per block: 448 frag + 64 mask. Two dense nt sweeps.
    const f32x4* s4 = (const f32x4*)s;

    f32x4* fdst = frag4 + (size_t)cell_base * F_OUT / 4;     // 448 f4 per block
    __builtin_nontemporal_store(s4[tid], &fdst[tid]);

    if (tid < 192) {
        __builtin_nontemporal_store(s4[256 + tid], &fdst[256 + tid]);
    } else {
        f32x4* mdst = mask4 + (cell_base >> 2);              // 64 f4 per block
        __builtin_nontemporal_store(s4[448 + (tid - 192)], &mdst[tid - 192]);
    }
}

extern "C" void kernel_launch(void* const* d_in, const int* in_sizes, int n_in,
                              void* d_out, int out_size, void* d_ws, size_t ws_size,
                              hipStream_t stream) {
    (void)n_in; (void)d_ws; (void)ws_size; (void)out_size;

    const float* x   = (const float*)d_in[0];
    float*       out = (float*)d_out;

    constexpr int F_IN        = 8;
    constexpr int G           = 131072;
    constexpr float INPUT_LEN = 1048576.0f;

    const int total_cells = in_sizes[0] / F_IN;          // 32 * 131072 = 4,194,304
    float* frag = out;                                   // [total_cells * 7]
    float* mask = out + (size_t)total_cells * F_OUT;     // [total_cells]
    // mask byte offset = total_cells*7*4 = 117,440,512 — 16B-aligned.

    const int blocks = total_cells / CPB;                // exact: 16384 blocks

    yolo_decode_kernel<<<blocks, BLOCK, 0, stream>>>(
        (const f32x4*)x, (f32x4*)frag, (f32x4*)mask,
        G - 1, INPUT_LEN / (float)G, INPUT_LEN * 0.5f);
}

// Round 5
// 218.608 us; speedup vs baseline: 1.0445x; 1.0445x over previous
//
#include <hip/hip_runtime.h>

// YOLO 1D (audio) detection decoder, CENTER_DURATION encoding.
// Input  x: [B=32, G=131072, F=8] fp32 (8 floats / cell, 32B-aligned)
// Output   : fragments [B, G, 7] fp32, then mask [B, G] fp32 (1.0/0.0),
//            concatenated flat in d_out (tuple return order).
//
// History (measured, bench dur = kernel + ~148.5us fixed harness overhead;
// model validated by r1: kernel +8us -> bench +7.8us):
//  r0: 32B-stride loads + LDS + scalar stores      : kernel ~79.5us
//  r1: CPT=4 lane-private 128B records             : kernel  ~87us (64-line reqs)
//  r3: 32B-stride loads + LDS + dense nt f4 stores : kernel ~79.5us
//  r4: DENSE 16B-stride loads + dense nt f4 stores : kernel ~79.5us
// => loads, stores, LDS layout all exonerated; kernel pinned at 2.5 TB/s
// while harness fills sustain 6.7 TB/s. The invariant is EXTERNAL: the
// 537MB poison fill preceding each iteration dirties the entire 256MB L3,
// and every kernel miss must evict+writeback a dirty line. 256MB own
// traffic + ~256MB dirty flush @ 6.5TB/s ~= 79us = the measured plateau.
//
// This version (single-variable A/B vs r4): NON-TEMPORAL LOADS. nt loads
// return data without allocating in L2/L3 -> no dirty-line eviction on our
// critical path; the fill's dirty lines stay resident and the NEXT fill
// re-hits them in-cache (cutting its HBM traffic as well).
//
// Structure (unchanged from r4): thread t nt-loads f4 #t and #t+256 of the
// block's input (lane-stride 16B, fully dense). Even lanes hold
// {conf,x1,x2,x3} (decode start/end+mask), odd lanes {x4..x7}
// (pass-through); conf crosses via one __shfl_xor. Outputs staged in LDS
// (stride-7 frag + stride-1 mask: <=2-way aliasing = free), then written as
// 512 dense f4/block (448 frag + 64 mask, wave-aligned split) with nt
// stores.
//
// __fadd_rn/__fmul_rn block FMA contraction so rintf (round-nearest-even,
// = jnp.round) sees bit-identical pre-round values vs the JAX reference.
// halfd = x2 * 524288.0f is exact (pure power-of-two scaling). Odd lanes
// compute garbage start/end from x5/x6 but discard via select (no traps).

constexpr int BLOCK = 256;
constexpr int F_OUT = 7;
constexpr int CPB   = 256;               // cells per block

typedef float f32x4 __attribute__((ext_vector_type(4)));

__global__ __launch_bounds__(BLOCK) void yolo_decode_kernel(
    const f32x4* __restrict__ in4,       // [total_cells * 2] float4
    f32x4* __restrict__ frag4,           // frag region as float4
    f32x4* __restrict__ mask4,           // mask region as float4
    int g_mask,                          // G - 1 (G is a power of two)
    float cell_coef,                     // INPUT_LENGTH / G   (= 8.0f)
    float half_coef)                     // INPUT_LENGTH * 0.5 (= 524288.0f)
{
    // 1792 frag dwords + 256 mask dwords = 2048 dwords = 8 KB.
    __shared__ float s[CPB * F_OUT + CPB];

    const int tid       = threadIdx.x;
    const int p         = tid & 1;               // 0: fields 0-3, 1: fields 4-7
    const int cell_base = blockIdx.x * CPB;

    // Dense NT loads: 512 f4 per block, lane-stride 16 B, two 4KB-apart
    // instructions per thread (independent -> both in flight), no L2/L3
    // allocation -> no dirty-line evictions in our window.
    const f32x4* pbase = in4 + (size_t)blockIdx.x * (2 * CPB);
    const f32x4 v0 = __builtin_nontemporal_load(&pbase[tid]);
    const f32x4 v1 = __builtin_nontemporal_load(&pbase[BLOCK + tid]);

    const int c0 = tid >> 1;                     // local cell of v0
    #pragma unroll
    for (int h = 0; h < 2; ++h) {
        const f32x4 v  = h ? v1 : v0;
        const int   cl = h ? (c0 + BLOCK / 2) : c0;      // local cell index
        const int   c  = cell_base + cl;                 // global cell

        const float confo = __shfl_xor(v.x, 1);          // partner's .x
        const bool  m     = (p ? confo : v.x) >= 0.5f;

        // Even-lane decode (odd lanes: discarded garbage).
        const float g      = (float)(c & g_mask);
        const float center = __fmul_rn(__fadd_rn(g, v.y), cell_coef);
        const float halfd  = __fmul_rn(v.z, half_coef);  // exact pow2 scale
        const float s_val  = rintf(__fadd_rn(center, -halfd));  // v_rndne_f32
        const float e_val  = rintf(__fadd_rn(center,  halfd));

        // 4 predicated LDS writes, parity-selected (no divergence).
        const int base = cl * F_OUT + p * 3;
        s[base + 0] = m ? (p ? v.x : s_val) : 0.0f;
        s[base + 1] = m ? (p ? v.y : e_val) : 0.0f;
        s[base + 2] = m ? (p ? v.z : v.w ) : 0.0f;
        const int   a3 = p ? (cl * F_OUT + 6) : (CPB * F_OUT + cl);
        const float w3 = p ? (m ? v.w : 0.0f) : (m ? 1.0f : 0.0f);
        s[a3] = w3;
    }

    __syncthreads();

    // 512 float4 per block: 448 frag + 64 mask. Two dense nt sweeps.
    const f32x4* s4 = (const f32x4*)s;

    f32x4* fdst = frag4 + (size_t)cell_base * F_OUT / 4;     // 448 f4 per block
    __builtin_nontemporal_store(s4[tid], &fdst[tid]);

    if (tid < 192) {
        __builtin_nontemporal_store(s4[256 + tid], &fdst[256 + tid]);
    } else {
        f32x4* mdst = mask4 + (cell_base >> 2);              // 64 f4 per block
        __builtin_nontemporal_store(s4[448 + (tid - 192)], &mdst[tid - 192]);
    }
}

extern "C" void kernel_launch(void* const* d_in, const int* in_sizes, int n_in,
                              void* d_out, int out_size, void* d_ws, size_t ws_size,
                              hipStream_t stream) {
    (void)n_in; (void)d_ws; (void)ws_size; (void)out_size;

    const float* x   = (const float*)d_in[0];
    float*       out = (float*)d_out;

    constexpr int F_IN        = 8;
    constexpr int G           = 131072;
    constexpr float INPUT_LEN = 1048576.0f;

    const int total_cells = in_sizes[0] / F_IN;          // 32 * 131072 = 4,194,304
    float* frag = out;                                   // [total_cells * 7]
    float* mask = out + (size_t)total_cells * F_OUT;     // [total_cells]
    // mask byte offset = total_cells*7*4 = 117,440,512 — 16B-aligned.

    const int blocks = total_cells / CPB;                // exact: 16384 blocks

    yolo_decode_kernel<<<blocks, BLOCK, 0, stream>>>(
        (const f32x4*)x, (f32x4*)frag, (f32x4*)mask,
        G - 1, INPUT_LEN / (float)G, INPUT_LEN * 0.5f);
}